// Round 2
// baseline (5765.429 us; speedup 1.0000x reference)
//
#include <hip/hip_runtime.h>
#include <hip/hip_bf16.h>

typedef unsigned short u16;
typedef unsigned int u32;
typedef __attribute__((ext_vector_type(8))) short s16x8;
typedef __attribute__((ext_vector_type(4))) float f32x4;

// ---------------- sizes ----------------
// B=128 S=256 E=128 U=512 C=3 ; ALL float tensors are f32 (reference dtype);
// we convert to bf16 on device for the MFMA path.
// ws layout (bytes):
//  [0)          cnt     : [2][2][256][2] int          = 8192
//  [8192)       h0ring  : [2][4][128][512] bf16       = 1048576
//  [+)          h1ring  : [2][4][128][512] bf16       = 1048576
//  [+)          logits  : [128][256][3] f32           = 393216
//  zero-region total = 2498560
//  [2498560)    X       : [256][128][128] bf16        = 8388608
//  [10887168)   Wg      : packed bf16 weights         = 13762560
static constexpr size_t OFF_CNT = 0;
static constexpr size_t OFF_H0  = 8192;
static constexpr size_t OFF_H1  = OFF_H0 + 1048576;
static constexpr size_t OFF_LOG = OFF_H1 + 1048576;
static constexpr size_t ZB      = OFF_LOG + 393216;     // 2498560
static constexpr size_t OFF_X   = ZB;
static constexpr size_t OFF_W   = OFF_X + 8388608;      // 10887168
// packed weight chain offsets in elements (u16):
static constexpr size_t CB_FW0 = 0;
static constexpr size_t CB_FW1 = 1327104;   // 32*64*648
static constexpr size_t CB_BW0 = 3440640;
static constexpr size_t CB_BW1 = 4767744;
static constexpr unsigned SMEM_BYTES = 64 * 1032 * 2;   // 132096 (layer-1 strip)

__device__ inline u16 f2bu(float f) {
    union { float f; u32 u; } v; v.f = f;
    u32 x = v.u;
    return (u16)((x + 0x7fffu + ((x >> 16) & 1u)) >> 16);  // RNE f32->bf16
}
__device__ inline float sigf(float x) {
    x = fminf(fmaxf(x, -30.f), 30.f);
    return 1.f / (1.f + __expf(-x));
}
__device__ inline float tanh_f(float x) {
    x = fminf(fmaxf(x, -15.f), 15.f);
    float e = __expf(2.f * x);
    return (e - 1.f) / (e + 1.f);
}

// ---------------- phase A kernels ----------------
__global__ void embed_k(const int* __restrict__ tokens, const float2* __restrict__ emb,
                        u32* __restrict__ Xo) {
    int sb = blockIdx.x;               // s*128 + b
    int b = sb & 127, s = sb >> 7;
    int tok = tokens[b * 256 + s];
    float2 v = emb[(size_t)tok * 64 + threadIdx.x];
    Xo[(size_t)sb * 64 + threadIdx.x] = (u32)f2bu(v.x) | ((u32)f2bu(v.y) << 16);
}

// pack [Wr;Wk] (f32 sources -> bf16) column-reordered (strip-gate-major), +8 row pad.
// dst[nn*(Kc+8) + krow], nn = strip*64 + g*16 + u, src col = g*512 + strip*16 + u
__global__ void wrepack_k(const float* __restrict__ Wr, const float* __restrict__ Wk,
                          u16* __restrict__ dst, int Kc) {
    int e = blockIdx.x * 256 + threadIdx.x;
    int krow = e % Kc;
    int nn = e / Kc;
    if (nn >= 2048) return;
    int i = nn >> 6, n = nn & 63;
    int g = n >> 4, u = n & 15;
    int col = g * 512 + i * 16 + u;
    float v = (krow < 512) ? Wr[(size_t)krow * 2048 + col]
                           : Wk[(size_t)(krow - 512) * 2048 + col];
    dst[(size_t)nn * (Kc + 8) + krow] = f2bu(v);
}

// ---------------- main persistent kernel ----------------
__device__ inline void waitcnt32(int* ptr) {
    if (threadIdx.x == 0) {
        while (__hip_atomic_load(ptr, __ATOMIC_RELAXED, __HIP_MEMORY_SCOPE_AGENT) < 32)
            __builtin_amdgcn_s_sleep(1);
        __threadfence();   // acquire: invalidate caches before reading h
    }
    __syncthreads();
}

template <int KT, int RLB>
__device__ __forceinline__ void gemm_step(const u16* __restrict__ Aa,
                                          const u16* __restrict__ Ab,
                                          const u16* __restrict__ wlds,
                                          int Kpad, int rowA, int qq, int uu,
                                          f32x4 acc[4]) {
    constexpr int PF = 4;
    const u16* abase = Aa + (size_t)rowA * 512 + qq * 8;
    const u16* bbase = Ab + (size_t)rowA * RLB + qq * 8;
    const u16* blds  = wlds + uu * Kpad + qq * 8;
    s16x8 ap[PF];
#pragma unroll
    for (int k0 = 0; k0 < PF; ++k0)
        ap[k0] = *(const s16x8*)(abase + k0 * 32);
#pragma unroll
    for (int kt = 0; kt < KT; ++kt) {
        s16x8 av = ap[kt % PF];
        int kn = kt + PF;
        if (kn < KT) {
            ap[kt % PF] = (kn < 16) ? *(const s16x8*)(abase + kn * 32)
                                    : *(const s16x8*)(bbase + (kn - 16) * 32);
        }
#pragma unroll
        for (int g = 0; g < 4; ++g) {
            s16x8 bv = *(const s16x8*)(blds + (g * 16) * Kpad + kt * 32);
            acc[g] = __builtin_amdgcn_mfma_f32_16x16x32_bf16(av, bv, acc[g], 0, 0, 0);
        }
    }
}

__global__ void __launch_bounds__(256, 1)
lstm_engine(const u16* __restrict__ Wg, const u16* __restrict__ X,
            u16* __restrict__ h0ring, u16* __restrict__ h1ring,
            int* __restrict__ cnt, float* __restrict__ logits,
            const float* __restrict__ bf0, const float* __restrict__ bf1,
            const float* __restrict__ bb0, const float* __restrict__ bb1,
            const float* __restrict__ dW) {
    extern __shared__ u16 wlds[];
    const int tid = threadIdx.x;
    const int bid = blockIdx.x;
    const int dir   = bid >> 7;        // 0 fw, 1 bw
    const int rr    = bid & 127;
    const int layer = rr >> 6;         // 0 or 1
    const int q     = rr & 63;
    const int strip = q >> 1;          // 0..31 (16 hidden units each)
    const int p     = q & 1;           // row block (64 rows)
    const int wv    = tid >> 6;        // wave 0..3
    const int lane  = tid & 63;
    const int uu    = lane & 15;       // unit-in-strip / A-row / C-col
    const int qq    = lane >> 4;       // quad

    const int Kc   = layer ? 1024 : 640;
    const int Kpad = Kc + 8;
    const size_t cbase = layer ? (dir ? CB_BW1 : CB_FW1) : (dir ? CB_BW0 : CB_FW0);
    const u16* wsrc = Wg + cbase + (size_t)strip * 64 * Kpad;

    {   // stage weight strip into LDS (one time)
        const uint4* s4 = (const uint4*)wsrc;
        uint4* d4 = (uint4*)wlds;
        const int n16 = (64 * Kpad) / 8;
        for (int j = tid; j < n16; j += 256) d4[j] = s4[j];
    }
    const float* bptr = layer ? (dir ? bb1 : bf1) : (dir ? bb0 : bf0);
    float bias[4];
#pragma unroll
    for (int g = 0; g < 4; ++g) bias[g] = bptr[g * 512 + strip * 16 + uu];
    float wd[3] = {0.f, 0.f, 0.f};
    if (layer) {
#pragma unroll
        for (int c = 0; c < 3; ++c) wd[c] = dW[(size_t)(dir * 512 + strip * 16 + uu) * 3 + c];
    }
    __syncthreads();

    u16* H0 = h0ring + (size_t)dir * (4 * 128 * 512);
    u16* H1 = h1ring + (size_t)dir * (4 * 128 * 512);
    int* cb = cnt + dir * (2 * 256 * 2);   // [layer][t][p]

    const int rowA = p * 64 + wv * 16 + uu;
    const int rowC = p * 64 + wv * 16 + qq * 4;

    float cst[4] = {0.f, 0.f, 0.f, 0.f};

    for (int t = 0; t < 256; ++t) {
        const u16 *Aa, *Ab;
        u16* Hout;
        if (layer == 0) {
            if (t > 0)  waitcnt32(&cb[(0 * 256 + (t - 1)) * 2 + p]);
            if (t >= 4) waitcnt32(&cb[(1 * 256 + (t - 4)) * 2 + p]);  // ring backpressure
            Aa = H0 + ((t - 1) & 3) * 65536;
            int tx = dir ? (255 - t) : t;
            Ab = X + (size_t)tx * (128 * 128);
            Hout = H0 + (t & 3) * 65536;
        } else {
            waitcnt32(&cb[(0 * 256 + t) * 2 + p]);                    // h0[t] ready
            if (t > 0) waitcnt32(&cb[(1 * 256 + (t - 1)) * 2 + p]);   // h1[t-1] ready
            Aa = H1 + ((t - 1) & 3) * 65536;
            Ab = H0 + (t & 3) * 65536;
            Hout = H1 + (t & 3) * 65536;
        }

        f32x4 acc[4];
#pragma unroll
        for (int g = 0; g < 4; ++g) acc[g] = (f32x4){bias[g], bias[g], bias[g], bias[g]};

        if (layer == 0) gemm_step<20, 128>(Aa, Ab, wlds, Kpad, rowA, qq, uu, acc);
        else            gemm_step<32, 512>(Aa, Ab, wlds, Kpad, rowA, qq, uu, acc);

        float hv[4];
#pragma unroll
        for (int j = 0; j < 4; ++j) {
            float iv = sigf(acc[0][j]);
            float fv = sigf(acc[1][j]);
            float gv = tanh_f(acc[2][j]);
            float ov = sigf(acc[3][j]);
            float cj = fv * cst[j] + iv * gv;
            cst[j] = cj;
            float h = ov * tanh_f(cj);
            hv[j] = h;
            Hout[(size_t)(rowC + j) * 512 + strip * 16 + uu] = f2bu(h);
        }

        if (layer) {   // fused dense: logits[b][s][c] += sum_u h*Wd
            int s_out = dir ? (255 - t) : t;
#pragma unroll
            for (int j = 0; j < 4; ++j) {
#pragma unroll
                for (int c = 0; c < 3; ++c) {
                    float v = hv[j] * wd[c];
                    v += __shfl_xor(v, 1);
                    v += __shfl_xor(v, 2);
                    v += __shfl_xor(v, 4);
                    v += __shfl_xor(v, 8);
                    if (uu == 0)
                        atomicAdd(&logits[((size_t)(rowC + j) * 256 + s_out) * 3 + c], v);
                }
            }
        }

        __syncthreads();   // all threads' h stores drained (vmcnt(0)) before flag
        if (tid == 0)
            __hip_atomic_fetch_add(&cb[(layer * 256 + t) * 2 + p], 1,
                                   __ATOMIC_RELEASE, __HIP_MEMORY_SCOPE_AGENT);
    }
}

__global__ void softmax_k(const float* __restrict__ logits, const float* __restrict__ db,
                          float* __restrict__ out) {
    int idx = blockIdx.x * 256 + threadIdx.x;   // b*256+s
    float l0 = logits[(size_t)idx * 3 + 0] + db[0];
    float l1 = logits[(size_t)idx * 3 + 1] + db[1];
    float l2 = logits[(size_t)idx * 3 + 2] + db[2];
    float m = fmaxf(l0, fmaxf(l1, l2));
    float e0 = __expf(l0 - m), e1 = __expf(l1 - m), e2 = __expf(l2 - m);
    float r = 1.f / (e0 + e1 + e2);
    out[(size_t)idx * 3 + 0] = e0 * r;
    out[(size_t)idx * 3 + 1] = e1 * r;
    out[(size_t)idx * 3 + 2] = e2 * r;
}

extern "C" void kernel_launch(void* const* d_in, const int* in_sizes, int n_in,
                              void* d_out, int out_size, void* d_ws, size_t ws_size,
                              hipStream_t stream) {
    (void)in_sizes; (void)n_in; (void)out_size; (void)ws_size;
    const int*   tokens = (const int*)d_in[0];
    const float2* emb   = (const float2*)d_in[1];
    const float* fw0_Wk = (const float*)d_in[2];
    const float* fw0_Wr = (const float*)d_in[3];
    const float* fw0_b  = (const float*)d_in[4];
    const float* fw1_Wk = (const float*)d_in[5];
    const float* fw1_Wr = (const float*)d_in[6];
    const float* fw1_b  = (const float*)d_in[7];
    const float* bw0_Wk = (const float*)d_in[8];
    const float* bw0_Wr = (const float*)d_in[9];
    const float* bw0_b  = (const float*)d_in[10];
    const float* bw1_Wk = (const float*)d_in[11];
    const float* bw1_Wr = (const float*)d_in[12];
    const float* bw1_b  = (const float*)d_in[13];
    const float* dW     = (const float*)d_in[14];
    const float* db     = (const float*)d_in[15];

    char* ws = (char*)d_ws;
    int*   cnt = (int*)(ws + OFF_CNT);
    u16*   H0  = (u16*)(ws + OFF_H0);
    u16*   H1  = (u16*)(ws + OFF_H1);
    float* lg  = (float*)(ws + OFF_LOG);
    u32*   Xw  = (u32*)(ws + OFF_X);
    const u16* Xr = (const u16*)(ws + OFF_X);
    u16*   Wg  = (u16*)(ws + OFF_W);
    const u16* Wgc = Wg;

    hipMemsetAsync(ws, 0, ZB, stream);
    embed_k<<<32768, 64, 0, stream>>>(tokens, emb, Xw);
    wrepack_k<<<5120, 256, 0, stream>>>(fw0_Wr, fw0_Wk, Wg + CB_FW0, 640);
    wrepack_k<<<8192, 256, 0, stream>>>(fw1_Wr, fw1_Wk, Wg + CB_FW1, 1024);
    wrepack_k<<<5120, 256, 0, stream>>>(bw0_Wr, bw0_Wk, Wg + CB_BW0, 640);
    wrepack_k<<<8192, 256, 0, stream>>>(bw1_Wr, bw1_Wk, Wg + CB_BW1, 1024);

    hipFuncSetAttribute((const void*)lstm_engine,
                        hipFuncAttributeMaxDynamicSharedMemorySize, SMEM_BYTES);
    void* args[] = { (void*)&Wgc, (void*)&Xr, (void*)&H0, (void*)&H1, (void*)&cnt,
                     (void*)&lg, (void*)&fw0_b, (void*)&fw1_b, (void*)&bw0_b,
                     (void*)&bw1_b, (void*)&dW };
    hipLaunchCooperativeKernel((const void*)lstm_engine, dim3(256), dim3(256),
                               args, SMEM_BYTES, stream);

    softmax_k<<<128, 256, 0, stream>>>(lg, db, (float*)d_out);
}

// Round 9
// 5215.768 us; speedup vs baseline: 1.1054x; 1.1054x over previous
//
#include <hip/hip_runtime.h>
#include <hip/hip_bf16.h>

typedef unsigned short u16;
typedef unsigned int u32;
typedef __attribute__((ext_vector_type(8))) short s16x8;
typedef __attribute__((ext_vector_type(4))) float f32x4;

// ---------------- sizes ----------------
// B=128 S=256 E=128 U=512 C=3 ; float inputs are f32, converted to bf16 on device.
// ws layout (bytes) — identical to the round-2 PASSING kernel:
//  [0)        cnt    : [2][2][256][2] int        = 8192
//  [8192)     h0ring : [2][4][128][512] bf16     = 1048576   (natural row-major)
//  [1056768)  h1ring : [2][4][128][512] bf16     = 1048576
//  [2105344)  logits : [128][256][3] f32         = 393216
//  ZB = 2498560 (zeroed each launch)
//  [2498560)  X      : [256][128][128] bf16      = 8388608
//  [10887168) Wg     : packed bf16 weights       = 13762560
static constexpr size_t OFF_CNT = 0;
static constexpr size_t OFF_H0  = 8192;
static constexpr size_t OFF_H1  = OFF_H0 + 1048576;
static constexpr size_t OFF_LOG = OFF_H1 + 1048576;
static constexpr size_t ZB      = OFF_LOG + 393216;     // 2498560
static constexpr size_t OFF_X   = ZB;
static constexpr size_t OFF_W   = OFF_X + 8388608;      // 10887168
// packed weight chain offsets in elements (u16):
static constexpr size_t CB_FW0 = 0;
static constexpr size_t CB_FW1 = 1327104;   // 32*64*648
static constexpr size_t CB_BW0 = 3440640;
static constexpr size_t CB_BW1 = 4767744;
static constexpr unsigned SMEM_BYTES = 64 * 1032 * 2;   // 132096 (layer-1 strip)

__device__ inline u16 f2bu(float f) {
    union { float f; u32 u; } v; v.f = f;
    u32 x = v.u;
    return (u16)((x + 0x7fffu + ((x >> 16) & 1u)) >> 16);  // RNE f32->bf16
}
__device__ inline float sigf(float x) {
    x = fminf(fmaxf(x, -30.f), 30.f);
    return 1.f / (1.f + __expf(-x));
}
__device__ inline float tanh_f(float x) {
    x = fminf(fmaxf(x, -15.f), 15.f);
    float e = __expf(2.f * x);
    return (e - 1.f) / (e + 1.f);
}

// ---------------- phase A kernels ----------------
__global__ void embed_k(const int* __restrict__ tokens, const float2* __restrict__ emb,
                        u32* __restrict__ Xo) {
    int sb = blockIdx.x;               // s*128 + b
    int b = sb & 127, s = sb >> 7;
    int tok = tokens[b * 256 + s];
    float2 v = emb[(size_t)tok * 64 + threadIdx.x];
    Xo[(size_t)sb * 64 + threadIdx.x] = (u32)f2bu(v.x) | ((u32)f2bu(v.y) << 16);
}

// pack [Wr;Wk] (f32 -> bf16) column-reordered (strip-gate-major), +8 row pad.
// dst[nn*(Kc+8) + krow], nn = strip*64 + g*16 + u, src col = g*512 + strip*16 + u
__global__ void wrepack_k(const float* __restrict__ Wr, const float* __restrict__ Wk,
                          u16* __restrict__ dst, int Kc) {
    int e = blockIdx.x * 256 + threadIdx.x;
    int krow = e % Kc;
    int nn = e / Kc;
    if (nn >= 2048) return;
    int i = nn >> 6, n = nn & 63;
    int g = n >> 4, u = n & 15;
    int col = g * 512 + i * 16 + u;
    float v = (krow < 512) ? Wr[(size_t)krow * 2048 + col]
                           : Wk[(size_t)(krow - 512) * 2048 + col];
    dst[(size_t)nn * (Kc + 8) + krow] = f2bu(v);
}

// ---------------- main persistent kernel ----------------
// ROUND-2-PROVEN sync: tid0 relaxed poll + threadfence (acquire: inv) + barrier.
// Watchdog: bounded spin (~7 ms/wait) converts any deadlock into a completed
// run with wrong output (diagnosable) instead of a dead container. Value-inert
// in normal operation (waits are ~µs; the break never fires).
__device__ inline void waitcnt32(int* ptr) {
    if (threadIdx.x == 0) {
        int spins = 0;
        while (__hip_atomic_load(ptr, __ATOMIC_RELAXED, __HIP_MEMORY_SCOPE_AGENT) < 32) {
            __builtin_amdgcn_s_sleep(2);
            if (++spins > (1 << 17)) break;   // ~16.8M cycles ≈ 7 ms watchdog
        }
        __threadfence();   // acquire: invalidate caches before reading h
    }
    __syncthreads();
}

template <int LAYER>
__device__ __forceinline__ void run_chain(
    const u16* __restrict__ wlds, const u16* __restrict__ X,
    u16* __restrict__ H0, u16* __restrict__ H1, int* __restrict__ cb,
    float* __restrict__ logits, const float* __restrict__ bptr,
    const float* __restrict__ dW,
    int dir, int p, int strip, int wv, int lane)
{
    constexpr int Kpad = LAYER ? 1032 : 648;
    const int tid  = threadIdx.x;
    const int uu   = lane & 15;
    const int qq   = lane >> 4;
    const int rowA = p * 64 + wv * 16 + uu;
    const int rowC = p * 64 + wv * 16 + qq * 4;
    const u16* blds = wlds + (size_t)uu * Kpad + qq * 8;

    float bias[4];
#pragma unroll
    for (int g = 0; g < 4; ++g) bias[g] = bptr[g * 512 + strip * 16 + uu];
    float wd[3] = {0.f, 0.f, 0.f};
    if (LAYER == 1) {
#pragma unroll
        for (int c = 0; c < 3; ++c)
            wd[c] = dW[(size_t)(dir * 512 + strip * 16 + uu) * 3 + c];
    }

    float cst[4] = {0.f, 0.f, 0.f, 0.f};

    for (int t = 0; t < 256; ++t) {
        s16x8 af[16], af2[16], xf[4];

        if (LAYER == 0) {
            // X prefetch into VGPRs BEFORE polls (read-only; survives the fence)
            int tx = dir ? (255 - t) : t;
            const u16* xb = X + (size_t)tx * 16384 + rowA * 128 + qq * 8;
#pragma unroll
            for (int j = 0; j < 4; ++j) xf[j] = *(const s16x8*)(xb + j * 32);

            if (t > 0)  waitcnt32(&cb[(0 * 256 + (t - 1)) * 2 + p]);  // h0[t-1]
            if (t >= 4) waitcnt32(&cb[(256 + (t - 4)) * 2 + p]);      // ring backpressure

            // batched plain loads of all 16 h0_prev fragments (one latency round)
            const u16* pa = H0 + ((t - 1) & 3) * 65536 + (size_t)rowA * 512 + qq * 8;
#pragma unroll
            for (int i = 0; i < 16; ++i) af[i] = *(const s16x8*)(pa + i * 32);
        } else {
            waitcnt32(&cb[(0 * 256 + t) * 2 + p]);                    // h0[t] ready
            // slack-edge loads (h0[t]) issued here: hidden under the tight wait below
            const u16* pb = H0 + (t & 3) * 65536 + (size_t)rowA * 512 + qq * 8;
#pragma unroll
            for (int i = 0; i < 16; ++i) af2[i] = *(const s16x8*)(pb + i * 32);

            if (t > 0) waitcnt32(&cb[(256 + (t - 1)) * 2 + p]);       // h1[t-1] (tight)
            const u16* pa = H1 + ((t - 1) & 3) * 65536 + (size_t)rowA * 512 + qq * 8;
#pragma unroll
            for (int i = 0; i < 16; ++i) af[i] = *(const s16x8*)(pa + i * 32);
        }

        f32x4 acc[4];
#pragma unroll
        for (int g = 0; g < 4; ++g)
            acc[g] = (f32x4){bias[g], bias[g], bias[g], bias[g]};

        // MFMA order identical to round 2: kt ascending, gate inner
#pragma unroll
        for (int kt = 0; kt < 16; ++kt) {
            s16x8 av = af[kt];
#pragma unroll
            for (int g = 0; g < 4; ++g) {
                s16x8 bv = *(const s16x8*)(blds + (size_t)g * 16 * Kpad + kt * 32);
                acc[g] = __builtin_amdgcn_mfma_f32_16x16x32_bf16(av, bv, acc[g], 0, 0, 0);
            }
        }
        if (LAYER == 0) {
#pragma unroll
            for (int j = 0; j < 4; ++j) {
                s16x8 av = xf[j];
#pragma unroll
                for (int g = 0; g < 4; ++g) {
                    s16x8 bv = *(const s16x8*)(blds + (size_t)g * 16 * Kpad + (16 + j) * 32);
                    acc[g] = __builtin_amdgcn_mfma_f32_16x16x32_bf16(av, bv, acc[g], 0, 0, 0);
                }
            }
        } else {
#pragma unroll
            for (int kt = 0; kt < 16; ++kt) {
                s16x8 av = af2[kt];
#pragma unroll
                for (int g = 0; g < 4; ++g) {
                    s16x8 bv = *(const s16x8*)(blds + (size_t)g * 16 * Kpad + (16 + kt) * 32);
                    acc[g] = __builtin_amdgcn_mfma_f32_16x16x32_bf16(av, bv, acc[g], 0, 0, 0);
                }
            }
        }

        // LSTM epilogue — round-2-identical natural-layout plain u16 stores
        u16* Hout = (LAYER == 0) ? H0 + (t & 3) * 65536 : H1 + (t & 3) * 65536;
        float hv[4];
#pragma unroll
        for (int j = 0; j < 4; ++j) {
            float iv = sigf(acc[0][j]);
            float fv = sigf(acc[1][j]);
            float gv = tanh_f(acc[2][j]);
            float ov = sigf(acc[3][j]);
            float cj = fv * cst[j] + iv * gv;
            cst[j] = cj;
            float h = ov * tanh_f(cj);
            hv[j] = h;
            Hout[(size_t)(rowC + j) * 512 + strip * 16 + uu] = f2bu(h);
        }

        if (LAYER == 1) {   // fused dense BEFORE the closing barrier (round-2 position)
            int s_out = dir ? (255 - t) : t;
#pragma unroll
            for (int j = 0; j < 4; ++j) {
#pragma unroll
                for (int c = 0; c < 3; ++c) {
                    float v = hv[j] * wd[c];
                    v += __shfl_xor(v, 1);
                    v += __shfl_xor(v, 2);
                    v += __shfl_xor(v, 4);
                    v += __shfl_xor(v, 8);
                    if (uu == 0)
                        atomicAdd(&logits[((size_t)(rowC + j) * 256 + s_out) * 3 + c], v);
                }
            }
        }

        __syncthreads();   // barrier lowering drains each wave's vmcnt
        if (tid == 0)      // RELEASE publish (round-2-proven)
            __hip_atomic_fetch_add(&cb[(LAYER * 256 + t) * 2 + p], 1,
                                   __ATOMIC_RELEASE, __HIP_MEMORY_SCOPE_AGENT);
    }
}

__global__ void __launch_bounds__(256, 1)
lstm_engine(const u16* __restrict__ Wg, const u16* __restrict__ X,
            u16* __restrict__ h0ring, u16* __restrict__ h1ring,
            int* __restrict__ cnt, float* __restrict__ logits,
            const float* __restrict__ bf0, const float* __restrict__ bf1,
            const float* __restrict__ bb0, const float* __restrict__ bb1,
            const float* __restrict__ dW) {
    extern __shared__ u16 wlds[];
    const int tid = threadIdx.x;
    const int bid = blockIdx.x;
    const int dir   = bid >> 7;        // 0 fw, 1 bw
    const int rr    = bid & 127;
    const int layer = rr >> 6;         // 0 or 1
    const int q     = rr & 63;
    const int strip = q >> 1;          // 0..31 (16 hidden units each)
    const int p     = q & 1;           // row block (64 rows)
    const int wv    = tid >> 6;        // wave 0..3
    const int lane  = tid & 63;

    const int Kc   = layer ? 1024 : 640;
    const int Kpad = Kc + 8;
    const size_t cbase = layer ? (dir ? CB_BW1 : CB_FW1) : (dir ? CB_BW0 : CB_FW0);
    const u16* wsrc = Wg + cbase + (size_t)strip * 64 * Kpad;

    {   // stage weight strip into LDS (one time)
        const uint4* s4 = (const uint4*)wsrc;
        uint4* d4 = (uint4*)wlds;
        const int n16 = (64 * Kpad) / 8;
        for (int j = tid; j < n16; j += 256) d4[j] = s4[j];
    }
    __syncthreads();

    u16* H0 = h0ring + (size_t)dir * (4 * 65536);
    u16* H1 = h1ring + (size_t)dir * (4 * 65536);
    int* cb = cnt + dir * (2 * 256 * 2);   // [layer][t][p]
    const float* bptr = layer ? (dir ? bb1 : bf1) : (dir ? bb0 : bf0);

    if (layer == 0)
        run_chain<0>(wlds, X, H0, H1, cb, logits, bptr, dW, dir, p, strip, wv, lane);
    else
        run_chain<1>(wlds, X, H0, H1, cb, logits, bptr, dW, dir, p, strip, wv, lane);
}

__global__ void softmax_k(const float* __restrict__ logits, const float* __restrict__ db,
                          float* __restrict__ out) {
    int idx = blockIdx.x * 256 + threadIdx.x;   // b*256+s
    float l0 = logits[(size_t)idx * 3 + 0] + db[0];
    float l1 = logits[(size_t)idx * 3 + 1] + db[1];
    float l2 = logits[(size_t)idx * 3 + 2] + db[2];
    float m = fmaxf(l0, fmaxf(l1, l2));
    float e0 = __expf(l0 - m), e1 = __expf(l1 - m), e2 = __expf(l2 - m);
    float r = 1.f / (e0 + e1 + e2);
    out[(size_t)idx * 3 + 0] = e0 * r;
    out[(size_t)idx * 3 + 1] = e1 * r;
    out[(size_t)idx * 3 + 2] = e2 * r;
}

extern "C" void kernel_launch(void* const* d_in, const int* in_sizes, int n_in,
                              void* d_out, int out_size, void* d_ws, size_t ws_size,
                              hipStream_t stream) {
    (void)in_sizes; (void)n_in; (void)out_size; (void)ws_size;
    const int*    tokens = (const int*)d_in[0];
    const float2* emb    = (const float2*)d_in[1];
    const float* fw0_Wk = (const float*)d_in[2];
    const float* fw0_Wr = (const float*)d_in[3];
    const float* fw0_b  = (const float*)d_in[4];
    const float* fw1_Wk = (const float*)d_in[5];
    const float* fw1_Wr = (const float*)d_in[6];
    const float* fw1_b  = (const float*)d_in[7];
    const float* bw0_Wk = (const float*)d_in[8];
    const float* bw0_Wr = (const float*)d_in[9];
    const float* bw0_b  = (const float*)d_in[10];
    const float* bw1_Wk = (const float*)d_in[11];
    const float* bw1_Wr = (const float*)d_in[12];
    const float* bw1_b  = (const float*)d_in[13];
    const float* dW     = (const float*)d_in[14];
    const float* db     = (const float*)d_in[15];

    char* ws = (char*)d_ws;
    int*   cnt = (int*)(ws + OFF_CNT);
    u16*   H0  = (u16*)(ws + OFF_H0);
    u16*   H1  = (u16*)(ws + OFF_H1);
    float* lg  = (float*)(ws + OFF_LOG);
    u32*   Xw  = (u32*)(ws + OFF_X);
    const u16* Xr = (const u16*)(ws + OFF_X);
    u16*   Wg  = (u16*)(ws + OFF_W);
    const u16* Wgc = Wg;

    hipMemsetAsync(ws, 0, ZB, stream);
    embed_k<<<32768, 64, 0, stream>>>(tokens, emb, Xw);
    wrepack_k<<<5120, 256, 0, stream>>>(fw0_Wr, fw0_Wk, Wg + CB_FW0, 640);
    wrepack_k<<<8192, 256, 0, stream>>>(fw1_Wr, fw1_Wk, Wg + CB_FW1, 1024);
    wrepack_k<<<5120, 256, 0, stream>>>(bw0_Wr, bw0_Wk, Wg + CB_BW0, 640);
    wrepack_k<<<8192, 256, 0, stream>>>(bw1_Wr, bw1_Wk, Wg + CB_BW1, 1024);

    hipFuncSetAttribute((const void*)lstm_engine,
                        hipFuncAttributeMaxDynamicSharedMemorySize, SMEM_BYTES);
    void* args[] = { (void*)&Wgc, (void*)&Xr, (void*)&H0, (void*)&H1, (void*)&cnt,
                     (void*)&lg, (void*)&fw0_b, (void*)&fw1_b, (void*)&bw0_b,
                     (void*)&bw1_b, (void*)&dW };
    hipLaunchCooperativeKernel((const void*)lstm_engine, dim3(256), dim3(256),
                               args, SMEM_BYTES, stream);

    softmax_k<<<128, 256, 0, stream>>>(lg, db, (float*)d_out);
}

// Round 10
// 4000.560 us; speedup vs baseline: 1.4412x; 1.3038x over previous
//
#include <hip/hip_runtime.h>
#include <hip/hip_bf16.h>

typedef unsigned short u16;
typedef unsigned int u32;
typedef __attribute__((ext_vector_type(8))) short s16x8;
typedef __attribute__((ext_vector_type(4))) float f32x4;

// ---------------- sizes ----------------
// B=128 S=256 E=128 U=512 C=3 ; float inputs are f32, converted to bf16 on device.
// ws layout (bytes) — identical to the round-2/9 PASSING kernels:
//  [0)        cnt    : [2][2][256][2] int        = 8192
//  [8192)     h0ring : [2][4][128][512] bf16     = 1048576   (natural row-major)
//  [1056768)  h1ring : [2][4][128][512] bf16     = 1048576
//  [2105344)  logits : [128][256][3] f32         = 393216
//  ZB = 2498560 (zeroed each launch)
//  [2498560)  X      : [256][128][128] bf16      = 8388608
//  [10887168) Wg     : packed bf16 weights       = 13762560
static constexpr size_t OFF_CNT = 0;
static constexpr size_t OFF_H0  = 8192;
static constexpr size_t OFF_H1  = OFF_H0 + 1048576;
static constexpr size_t OFF_LOG = OFF_H1 + 1048576;
static constexpr size_t ZB      = OFF_LOG + 393216;     // 2498560
static constexpr size_t OFF_X   = ZB;
static constexpr size_t OFF_W   = OFF_X + 8388608;      // 10887168
// packed weight chain offsets in elements (u16):
static constexpr size_t CB_FW0 = 0;
static constexpr size_t CB_FW1 = 1327104;   // 32*64*648
static constexpr size_t CB_BW0 = 3440640;
static constexpr size_t CB_BW1 = 4767744;
static constexpr unsigned SMEM_BYTES = 64 * 1032 * 2;   // 132096 (layer-1 strip)

__device__ inline u16 f2bu(float f) {
    union { float f; u32 u; } v; v.f = f;
    u32 x = v.u;
    return (u16)((x + 0x7fffu + ((x >> 16) & 1u)) >> 16);  // RNE f32->bf16
}
__device__ inline float sigf(float x) {
    x = fminf(fmaxf(x, -30.f), 30.f);
    return 1.f / (1.f + __expf(-x));
}
__device__ inline float tanh_f(float x) {
    x = fminf(fmaxf(x, -15.f), 15.f);
    float e = __expf(2.f * x);
    return (e - 1.f) / (e + 1.f);
}

// ---------------- phase A kernels ----------------
__global__ void embed_k(const int* __restrict__ tokens, const float2* __restrict__ emb,
                        u32* __restrict__ Xo) {
    int sb = blockIdx.x;               // s*128 + b
    int b = sb & 127, s = sb >> 7;
    int tok = tokens[b * 256 + s];
    float2 v = emb[(size_t)tok * 64 + threadIdx.x];
    Xo[(size_t)sb * 64 + threadIdx.x] = (u32)f2bu(v.x) | ((u32)f2bu(v.y) << 16);
}

// pack [Wr;Wk] (f32 -> bf16) column-reordered (strip-gate-major), +8 row pad.
// dst[nn*(Kc+8) + krow], nn = strip*64 + g*16 + u, src col = g*512 + strip*16 + u
__global__ void wrepack_k(const float* __restrict__ Wr, const float* __restrict__ Wk,
                          u16* __restrict__ dst, int Kc) {
    int e = blockIdx.x * 256 + threadIdx.x;
    int krow = e % Kc;
    int nn = e / Kc;
    if (nn >= 2048) return;
    int i = nn >> 6, n = nn & 63;
    int g = n >> 4, u = n & 15;
    int col = g * 512 + i * 16 + u;
    float v = (krow < 512) ? Wr[(size_t)krow * 2048 + col]
                           : Wk[(size_t)(krow - 512) * 2048 + col];
    dst[(size_t)nn * (Kc + 8) + krow] = f2bu(v);
}

// ---------------- main persistent kernel ----------------
// Merged dual-flag wait: tid0 polls both flags (watchdog-bounded), then ONE
// acquire-only agent fence (buffer_inv, no wbl2 — the reader has no dirty
// lines: its own stores were flushed by its previous RELEASE). Cacheops per
// WG-step drop 5 -> 2 vs round 9's dual seq_cst threadfence protocol.
__device__ inline void wait2(int* a, int* b) {
    if (threadIdx.x == 0) {
        int spins = 0;
        if (a) while (__hip_atomic_load(a, __ATOMIC_RELAXED, __HIP_MEMORY_SCOPE_AGENT) < 32) {
            __builtin_amdgcn_s_sleep(2);
            if (++spins > (1 << 17)) break;   // ~7 ms watchdog
        }
        if (b) while (__hip_atomic_load(b, __ATOMIC_RELAXED, __HIP_MEMORY_SCOPE_AGENT) < 32) {
            __builtin_amdgcn_s_sleep(2);
            if (++spins > (1 << 17)) break;
        }
        __builtin_amdgcn_fence(__ATOMIC_ACQUIRE, "agent");   // inv only
    }
    __syncthreads();
}

template <int LAYER>
__device__ __forceinline__ void run_chain(
    const u16* __restrict__ wlds, const u16* __restrict__ X,
    u16* __restrict__ H0, u16* __restrict__ H1, int* __restrict__ cb,
    float* __restrict__ logits, const float* __restrict__ bptr,
    const float* __restrict__ dW,
    int dir, int p, int strip, int wv, int lane)
{
    constexpr int Kpad = LAYER ? 1032 : 648;
    const int tid  = threadIdx.x;
    const int uu   = lane & 15;
    const int qq   = lane >> 4;
    const int rowA = p * 64 + wv * 16 + uu;
    const int rowC = p * 64 + wv * 16 + qq * 4;
    const u16* blds = wlds + (size_t)uu * Kpad + qq * 8;

    float bias[4];
#pragma unroll
    for (int g = 0; g < 4; ++g) bias[g] = bptr[g * 512 + strip * 16 + uu];
    float wd[3] = {0.f, 0.f, 0.f};
    if (LAYER == 1) {
#pragma unroll
        for (int c = 0; c < 3; ++c)
            wd[c] = dW[(size_t)(dir * 512 + strip * 16 + uu) * 3 + c];
    }

    float cst[4] = {0.f, 0.f, 0.f, 0.f};

    for (int t = 0; t < 256; ++t) {
        s16x8 af[16], af2[16], xf[4];

        if (LAYER == 0) {
            // X prefetch into VGPRs BEFORE the wait (read-only; survives the inv)
            int tx = dir ? (255 - t) : t;
            const u16* xb = X + (size_t)tx * 16384 + rowA * 128 + qq * 8;
#pragma unroll
            for (int j = 0; j < 4; ++j) xf[j] = *(const s16x8*)(xb + j * 32);

            // ONE merged wait: h0[t-1] data flag + ring backpressure flag
            int* fa = (t > 0)  ? &cb[(0 * 256 + (t - 1)) * 2 + p] : nullptr;
            int* fb = (t >= 4) ? &cb[(256 + (t - 4)) * 2 + p]     : nullptr;
            if (fa || fb) wait2(fa, fb);

            // batched plain loads of all 16 h0_prev fragments (one latency round)
            const u16* pa = H0 + ((t - 1) & 3) * 65536 + (size_t)rowA * 512 + qq * 8;
#pragma unroll
            for (int i = 0; i < 16; ++i) af[i] = *(const s16x8*)(pa + i * 32);
        } else {
            // ONE merged wait: h0[t] flag + h1[t-1] flag, single acquire fence
            int* fa = &cb[(0 * 256 + t) * 2 + p];
            int* fb = (t > 0) ? &cb[(256 + (t - 1)) * 2 + p] : nullptr;
            wait2(fa, fb);

            const u16* pb = H0 + (t & 3) * 65536 + (size_t)rowA * 512 + qq * 8;
#pragma unroll
            for (int i = 0; i < 16; ++i) af2[i] = *(const s16x8*)(pb + i * 32);
            const u16* pa = H1 + ((t - 1) & 3) * 65536 + (size_t)rowA * 512 + qq * 8;
#pragma unroll
            for (int i = 0; i < 16; ++i) af[i] = *(const s16x8*)(pa + i * 32);
        }

        f32x4 acc[4];
#pragma unroll
        for (int g = 0; g < 4; ++g)
            acc[g] = (f32x4){bias[g], bias[g], bias[g], bias[g]};

        // MFMA order identical to rounds 2/9: kt ascending, gate inner
#pragma unroll
        for (int kt = 0; kt < 16; ++kt) {
            s16x8 av = af[kt];
#pragma unroll
            for (int g = 0; g < 4; ++g) {
                s16x8 bv = *(const s16x8*)(blds + (size_t)g * 16 * Kpad + kt * 32);
                acc[g] = __builtin_amdgcn_mfma_f32_16x16x32_bf16(av, bv, acc[g], 0, 0, 0);
            }
        }
        if (LAYER == 0) {
#pragma unroll
            for (int j = 0; j < 4; ++j) {
                s16x8 av = xf[j];
#pragma unroll
                for (int g = 0; g < 4; ++g) {
                    s16x8 bv = *(const s16x8*)(blds + (size_t)g * 16 * Kpad + (16 + j) * 32);
                    acc[g] = __builtin_amdgcn_mfma_f32_16x16x32_bf16(av, bv, acc[g], 0, 0, 0);
                }
            }
        } else {
#pragma unroll
            for (int kt = 0; kt < 16; ++kt) {
                s16x8 av = af2[kt];
#pragma unroll
                for (int g = 0; g < 4; ++g) {
                    s16x8 bv = *(const s16x8*)(blds + (size_t)g * 16 * Kpad + (16 + kt) * 32);
                    acc[g] = __builtin_amdgcn_mfma_f32_16x16x32_bf16(av, bv, acc[g], 0, 0, 0);
                }
            }
        }

        // LSTM epilogue — natural-layout plain u16 stores (round-2/9-identical)
        u16* Hout = (LAYER == 0) ? H0 + (t & 3) * 65536 : H1 + (t & 3) * 65536;
        float hv[4];
#pragma unroll
        for (int j = 0; j < 4; ++j) {
            float iv = sigf(acc[0][j]);
            float fv = sigf(acc[1][j]);
            float gv = tanh_f(acc[2][j]);
            float ov = sigf(acc[3][j]);
            float cj = fv * cst[j] + iv * gv;
            cst[j] = cj;
            float h = ov * tanh_f(cj);
            hv[j] = h;
            Hout[(size_t)(rowC + j) * 512 + strip * 16 + uu] = f2bu(h);
        }

        if (LAYER == 1) {   // fused dense BEFORE the closing barrier (proven position)
            int s_out = dir ? (255 - t) : t;
#pragma unroll
            for (int j = 0; j < 4; ++j) {
#pragma unroll
                for (int c = 0; c < 3; ++c) {
                    float v = hv[j] * wd[c];
                    v += __shfl_xor(v, 1);
                    v += __shfl_xor(v, 2);
                    v += __shfl_xor(v, 4);
                    v += __shfl_xor(v, 8);
                    if (uu == 0)
                        atomicAdd(&logits[((size_t)(rowC + j) * 256 + s_out) * 3 + c], v);
                }
            }
        }

        __syncthreads();   // barrier lowering drains each wave's vmcnt
        if (tid == 0)      // RELEASE publish (wbl2 — writer side, hardware-proven)
            __hip_atomic_fetch_add(&cb[(LAYER * 256 + t) * 2 + p], 1,
                                   __ATOMIC_RELEASE, __HIP_MEMORY_SCOPE_AGENT);
    }
}

__global__ void __launch_bounds__(256, 1)
lstm_engine(const u16* __restrict__ Wg, const u16* __restrict__ X,
            u16* __restrict__ h0ring, u16* __restrict__ h1ring,
            int* __restrict__ cnt, float* __restrict__ logits,
            const float* __restrict__ bf0, const float* __restrict__ bf1,
            const float* __restrict__ bb0, const float* __restrict__ bb1,
            const float* __restrict__ dW) {
    extern __shared__ u16 wlds[];
    const int tid = threadIdx.x;
    const int bid = blockIdx.x;
    const int dir   = bid >> 7;        // 0 fw, 1 bw
    const int rr    = bid & 127;
    const int layer = rr >> 6;         // 0 or 1
    const int q     = rr & 63;
    const int strip = q >> 1;          // 0..31 (16 hidden units each)
    const int p     = q & 1;           // row block (64 rows)
    const int wv    = tid >> 6;        // wave 0..3
    const int lane  = tid & 63;

    const int Kc   = layer ? 1024 : 640;
    const int Kpad = Kc + 8;
    const size_t cbase = layer ? (dir ? CB_BW1 : CB_FW1) : (dir ? CB_BW0 : CB_FW0);
    const u16* wsrc = Wg + cbase + (size_t)strip * 64 * Kpad;

    {   // stage weight strip into LDS (one time)
        const uint4* s4 = (const uint4*)wsrc;
        uint4* d4 = (uint4*)wlds;
        const int n16 = (64 * Kpad) / 8;
        for (int j = tid; j < n16; j += 256) d4[j] = s4[j];
    }
    __syncthreads();

    u16* H0 = h0ring + (size_t)dir * (4 * 65536);
    u16* H1 = h1ring + (size_t)dir * (4 * 65536);
    int* cb = cnt + dir * (2 * 256 * 2);   // [layer][t][p]
    const float* bptr = layer ? (dir ? bb1 : bf1) : (dir ? bb0 : bf0);

    if (layer == 0)
        run_chain<0>(wlds, X, H0, H1, cb, logits, bptr, dW, dir, p, strip, wv, lane);
    else
        run_chain<1>(wlds, X, H0, H1, cb, logits, bptr, dW, dir, p, strip, wv, lane);
}

__global__ void softmax_k(const float* __restrict__ logits, const float* __restrict__ db,
                          float* __restrict__ out) {
    int idx = blockIdx.x * 256 + threadIdx.x;   // b*256+s
    float l0 = logits[(size_t)idx * 3 + 0] + db[0];
    float l1 = logits[(size_t)idx * 3 + 1] + db[1];
    float l2 = logits[(size_t)idx * 3 + 2] + db[2];
    float m = fmaxf(l0, fmaxf(l1, l2));
    float e0 = __expf(l0 - m), e1 = __expf(l1 - m), e2 = __expf(l2 - m);
    float r = 1.f / (e0 + e1 + e2);
    out[(size_t)idx * 3 + 0] = e0 * r;
    out[(size_t)idx * 3 + 1] = e1 * r;
    out[(size_t)idx * 3 + 2] = e2 * r;
}

extern "C" void kernel_launch(void* const* d_in, const int* in_sizes, int n_in,
                              void* d_out, int out_size, void* d_ws, size_t ws_size,
                              hipStream_t stream) {
    (void)in_sizes; (void)n_in; (void)out_size; (void)ws_size;
    const int*    tokens = (const int*)d_in[0];
    const float2* emb    = (const float2*)d_in[1];
    const float* fw0_Wk = (const float*)d_in[2];
    const float* fw0_Wr = (const float*)d_in[3];
    const float* fw0_b  = (const float*)d_in[4];
    const float* fw1_Wk = (const float*)d_in[5];
    const float* fw1_Wr = (const float*)d_in[6];
    const float* fw1_b  = (const float*)d_in[7];
    const float* bw0_Wk = (const float*)d_in[8];
    const float* bw0_Wr = (const float*)d_in[9];
    const float* bw0_b  = (const float*)d_in[10];
    const float* bw1_Wk = (const float*)d_in[11];
    const float* bw1_Wr = (const float*)d_in[12];
    const float* bw1_b  = (const float*)d_in[13];
    const float* dW     = (const float*)d_in[14];
    const float* db     = (const float*)d_in[15];

    char* ws = (char*)d_ws;
    int*   cnt = (int*)(ws + OFF_CNT);
    u16*   H0  = (u16*)(ws + OFF_H0);
    u16*   H1  = (u16*)(ws + OFF_H1);
    float* lg  = (float*)(ws + OFF_LOG);
    u32*   Xw  = (u32*)(ws + OFF_X);
    const u16* Xr = (const u16*)(ws + OFF_X);
    u16*   Wg  = (u16*)(ws + OFF_W);
    const u16* Wgc = Wg;

    hipMemsetAsync(ws, 0, ZB, stream);
    embed_k<<<32768, 64, 0, stream>>>(tokens, emb, Xw);
    wrepack_k<<<5120, 256, 0, stream>>>(fw0_Wr, fw0_Wk, Wg + CB_FW0, 640);
    wrepack_k<<<8192, 256, 0, stream>>>(fw1_Wr, fw1_Wk, Wg + CB_FW1, 1024);
    wrepack_k<<<5120, 256, 0, stream>>>(bw0_Wr, bw0_Wk, Wg + CB_BW0, 640);
    wrepack_k<<<8192, 256, 0, stream>>>(bw1_Wr, bw1_Wk, Wg + CB_BW1, 1024);

    hipFuncSetAttribute((const void*)lstm_engine,
                        hipFuncAttributeMaxDynamicSharedMemorySize, SMEM_BYTES);
    void* args[] = { (void*)&Wgc, (void*)&Xr, (void*)&H0, (void*)&H1, (void*)&cnt,
                     (void*)&lg, (void*)&fw0_b, (void*)&fw1_b, (void*)&bw0_b,
                     (void*)&bw1_b, (void*)&dW };
    hipLaunchCooperativeKernel((const void*)lstm_engine, dim3(256), dim3(256),
                               args, SMEM_BYTES, stream);

    softmax_k<<<128, 256, 0, stream>>>(lg, db, (float*)d_out);
}